// Round 3
// baseline (550.897 us; speedup 1.0000x reference)
//
#include <hip/hip_runtime.h>
#include <cstdint>
#include <cstddef>

typedef _Float16 f16;
typedef __attribute__((ext_vector_type(4))) _Float16 f16x4;
typedef __attribute__((ext_vector_type(8))) _Float16 f16x8;
typedef __attribute__((ext_vector_type(4))) float f32x4;

#define NB 2
#define SEQ 2048
#define DM 2048
#define NH 8
#define HD 256
#define MT (NB * SEQ)   // 4096

// S*scaling in log2 units: Q pre-scaled by 0.0625*log2(e); exp2 offset 16*log2(e)
#define QSCALE 0.09016844f
#define CEXP   23.08312065f

// ---------------------------------------------------------------------------
// global -> LDS direct copy, 16B per lane. LDS dest must be wave-uniform base.
__device__ __forceinline__ void gload16(const f16* g, f16* l) {
    __builtin_amdgcn_global_load_lds(
        (const __attribute__((address_space(1))) uint32_t*)(const void*)g,
        (__attribute__((address_space(3))) uint32_t*)(void*)l,
        16, 0, 0);
}

// ---------------------------------------------------------------------------
// f32 -> f16 conversion (vectorized, grid-stride)
__global__ __launch_bounds__(256) void k_cvt(const float* __restrict__ src,
                                             f16* __restrict__ dst, int n) {
    for (int i = (blockIdx.x * blockDim.x + threadIdx.x) * 4; i < n;
         i += gridDim.x * blockDim.x * 4) {
        f32x4 v = *(const f32x4*)(src + i);
        f16x4 h;
        h[0] = (f16)v[0]; h[1] = (f16)v[1]; h[2] = (f16)v[2]; h[3] = (f16)v[3];
        *(f16x4*)(dst + i) = h;
    }
}

// ---------------------------------------------------------------------------
// 128x128 tile GEMM core (m97 structure): C = A[M,K] * B[N,K]^T
__device__ __forceinline__ void gemm128_core(const f16* __restrict__ A,
                                             const f16* __restrict__ B,
                                             int m0, int n0,
                                             f16* As, f16* Bs,
                                             f32x4 acc[4][4]) {
    const int tid  = threadIdx.x;
    const int wave = tid >> 6, lane = tid & 63;
    const int wr = (wave >> 1) << 6, wc = (wave & 1) << 6;
    const int lr = lane & 15;            // row within 16
    const int lk = (lane >> 4) << 3;     // k elem offset (0,8,16,24)

    for (int k0 = 0; k0 < DM; k0 += 32) {
        __syncthreads();
#pragma unroll
        for (int j = 0; j < 2; ++j) {
            int base = (j * 4 + wave) << 9;          // 512 elems per wave-issue
            int flat = base + (lane << 3);
            int r = flat >> 5, c = flat & 31;
            gload16(A + (size_t)(m0 + r) * DM + k0 + c, As + base);
            gload16(B + (size_t)(n0 + r) * DM + k0 + c, Bs + base);
        }
        __syncthreads();
        f16x8 af[4], bf[4];
#pragma unroll
        for (int mi = 0; mi < 4; ++mi)
            af[mi] = *(const f16x8*)&As[(wr + mi * 16 + lr) * 32 + lk];
#pragma unroll
        for (int nj = 0; nj < 4; ++nj)
            bf[nj] = *(const f16x8*)&Bs[(wc + nj * 16 + lr) * 32 + lk];
        __builtin_amdgcn_s_setprio(1);
#pragma unroll
        for (int mi = 0; mi < 4; ++mi)
#pragma unroll
            for (int nj = 0; nj < 4; ++nj)
                acc[mi][nj] = __builtin_amdgcn_mfma_f32_16x16x32_f16(
                    af[mi], bf[nj], acc[mi][nj], 0, 0, 0);
        __builtin_amdgcn_s_setprio(0);
    }
}

// ---------------------------------------------------------------------------
// QKV projection: y = x @ W^T + b ; Q scaled by QSCALE; Q,K -> [b,h,s,d], V -> [b,h,d,s]
__global__ __launch_bounds__(256) void k_proj_qkv(
    const f16* __restrict__ xh, const f16* __restrict__ Wq,
    const f16* __restrict__ Wk, const f16* __restrict__ Wv,
    const float* __restrict__ bq, const float* __restrict__ bk,
    const float* __restrict__ bv,
    f16* __restrict__ Qh, f16* __restrict__ Kh, f16* __restrict__ Vth) {
    __shared__ __align__(16) f16 As[128 * 32];
    __shared__ __align__(16) f16 Bs[128 * 32];
    const int mode = blockIdx.z;
    const f16* W = (mode == 0) ? Wq : (mode == 1) ? Wk : Wv;
    const float* bias = (mode == 0) ? bq : (mode == 1) ? bk : bv;

    const int m0 = blockIdx.y * 128, n0 = blockIdx.x * 128;
    f32x4 acc[4][4];
#pragma unroll
    for (int mi = 0; mi < 4; ++mi)
#pragma unroll
        for (int nj = 0; nj < 4; ++nj) acc[mi][nj] = (f32x4){0.f, 0.f, 0.f, 0.f};

    gemm128_core(xh, W, m0, n0, As, Bs, acc);

    const int lane = threadIdx.x & 63, wave = threadIdx.x >> 6;
    const int wr = (wave >> 1) << 6, wc = (wave & 1) << 6;
    const int lr = lane & 15, lg = lane >> 4;
#pragma unroll
    for (int nj = 0; nj < 4; ++nj) {
        int n = n0 + wc + nj * 16 + lr;
        float bb = bias[n];
        int h = n >> 8, d = n & 255;
#pragma unroll
        for (int mi = 0; mi < 4; ++mi) {
#pragma unroll
            for (int i = 0; i < 4; ++i) {
                int m = m0 + wr + mi * 16 + lg * 4 + i;
                int b = m >> 11, s = m & 2047;
                float v = acc[mi][nj][i] + bb;
                size_t bh = (size_t)(b * NH + h);
                if (mode == 0)
                    Qh[((bh * SEQ + s) << 8) + d] = (f16)(v * QSCALE);
                else if (mode == 1)
                    Kh[((bh * SEQ + s) << 8) + d] = (f16)v;
                else
                    Vth[((bh * HD + d) << 11) + s] = (f16)v;
            }
        }
    }
}

// ---------------------------------------------------------------------------
// Output projection: out = O @ Wo^T + bo  (f32 out)
__global__ __launch_bounds__(256) void k_proj_o(
    const f16* __restrict__ Oh, const f16* __restrict__ Wo,
    const float* __restrict__ bo, float* __restrict__ out) {
    __shared__ __align__(16) f16 As[128 * 32];
    __shared__ __align__(16) f16 Bs[128 * 32];
    const int m0 = blockIdx.y * 128, n0 = blockIdx.x * 128;
    f32x4 acc[4][4];
#pragma unroll
    for (int mi = 0; mi < 4; ++mi)
#pragma unroll
        for (int nj = 0; nj < 4; ++nj) acc[mi][nj] = (f32x4){0.f, 0.f, 0.f, 0.f};

    gemm128_core(Oh, Wo, m0, n0, As, Bs, acc);

    const int lane = threadIdx.x & 63, wave = threadIdx.x >> 6;
    const int wr = (wave >> 1) << 6, wc = (wave & 1) << 6;
    const int lr = lane & 15, lg = lane >> 4;
#pragma unroll
    for (int nj = 0; nj < 4; ++nj) {
        int n = n0 + wc + nj * 16 + lr;
        float bb = bo[n];
#pragma unroll
        for (int mi = 0; mi < 4; ++mi) {
#pragma unroll
            for (int i = 0; i < 4; ++i) {
                int m = m0 + wr + mi * 16 + lg * 4 + i;
                out[(size_t)m * DM + n] = acc[mi][nj][i] + bb;
            }
        }
    }
}

// ---------------------------------------------------------------------------
// Fused causal attention. KVBLK=32, LDS 37KB -> 4 blocks/CU.
// Fixed-max softmax (exact: shift-invariant; exp2 args bounded), so pass A is
// QK^T + masked exp2 + per-lane partial sums; single shfl-reduce at the end.
// Pass B recomputes S, writes normalized P (wide f32 stores), O += P*V.
__global__ __launch_bounds__(256, 4) void k_attn(
    const f16* __restrict__ Qh, const f16* __restrict__ Kh,
    const f16* __restrict__ Vth, float* __restrict__ P,
    f16* __restrict__ Oh) {
    __shared__ __align__(16) f16 Kl[32 * 256];     // [k-row][d] swizzled, 16KB
    __shared__ __align__(16) f16 Vl[256 * 32];     // [d][k-row] swizzled, 16KB
    __shared__ __align__(16) f16 Ps[4][16][40];    // per-wave P tile (pad 8)

    const int L = blockIdx.x;
    const int half = L >> 8, p = L & 255;
    const int h = p >> 5;
    const int qb = half ? (p & 31) : (31 - (p & 31));
    const int b = half;

    const int q0 = qb * 64;
    const int tid = threadIdx.x, wave = tid >> 6, lane = tid & 63;
    const int lr = lane & 15, lg = lane >> 4;
    const size_t bh = (size_t)(b * NH + h);
    const f16* Qb = Qh + (bh << 19);
    const f16* Kb = Kh + (bh << 19);
    const f16* Vb = Vth + (bh << 19);
    float* Pb = P + (bh << 22);

    const int kswz = (lr & 7) << 3;   // K read-side XOR (elem units)
    const int vswz = (lr & 3) << 3;   // V read-side XOR

    // Q fragments in registers (16 q-rows x 256 d per wave)
    f16x8 aq[8];
    {
        const f16* qrow = Qb + (size_t)(q0 + wave * 16 + lr) * HD + lg * 8;
#pragma unroll
        for (int kk = 0; kk < 8; ++kk) aq[kk] = *(const f16x8*)(qrow + kk * 32);
    }

    const int rowb = q0 + wave * 16 + lg * 4;  // +i gives absolute q row
    const int nt = 2 * qb + 2;                 // 32-wide k tiles

    float psum[4] = {0.f, 0.f, 0.f, 0.f};

    // ---------------- PASS A: row sums (fixed max) ----------------
    for (int kt = 0; kt < nt; ++kt) {
        __syncthreads();
#pragma unroll
        for (int j = 0; j < 4; ++j) {
            int base = (j * 4 + wave) << 9;
            int flat = base + (lane << 3);
            int r = flat >> 8;
            int c = (flat & 255) ^ ((r & 7) << 3);   // inverse-swizzled source
            gload16(Kb + (size_t)(kt * 32 + r) * HD + c, Kl + base);
        }
        __syncthreads();
        f32x4 s[2];
        s[0] = (f32x4){0.f, 0.f, 0.f, 0.f};
        s[1] = (f32x4){0.f, 0.f, 0.f, 0.f};
        __builtin_amdgcn_s_setprio(1);
#pragma unroll
        for (int kk = 0; kk < 8; ++kk) {
#pragma unroll
            for (int nj = 0; nj < 2; ++nj) {
                f16x8 bk = *(const f16x8*)&Kl[(nj * 16 + lr) * 256 +
                                              ((kk * 32 + lg * 8) ^ kswz)];
                s[nj] = __builtin_amdgcn_mfma_f32_16x16x32_f16(aq[kk], bk, s[nj], 0, 0, 0);
            }
        }
        __builtin_amdgcn_s_setprio(0);
        const int colb = kt * 32 + lr;
#pragma unroll
        for (int i = 0; i < 4; ++i) {
            int row = rowb + i;
#pragma unroll
            for (int nj = 0; nj < 2; ++nj)
                psum[i] += (colb + nj * 16 <= row) ? exp2f(s[nj][i] - CEXP) : 0.f;
        }
    }

    float inv[4];
#pragma unroll
    for (int i = 0; i < 4; ++i) {
        float l = psum[i];
        l += __shfl_xor(l, 1);
        l += __shfl_xor(l, 2);
        l += __shfl_xor(l, 4);
        l += __shfl_xor(l, 8);
        inv[i] = 1.f / l;
    }

    f32x4 o[16];
#pragma unroll
    for (int n = 0; n < 16; ++n) o[n] = (f32x4){0.f, 0.f, 0.f, 0.f};

    // ---------------- PASS B: P write + O accumulate ----------------
    for (int kt = 0; kt < nt; ++kt) {
        __syncthreads();
#pragma unroll
        for (int j = 0; j < 4; ++j) {
            int base = (j * 4 + wave) << 9;
            int flat = base + (lane << 3);
            int rk = flat >> 8;
            int ck = (flat & 255) ^ ((rk & 7) << 3);
            gload16(Kb + (size_t)(kt * 32 + rk) * HD + ck, Kl + base);
            int rv = flat >> 5;
            int cv = (flat & 31) ^ ((rv & 3) << 3);
            gload16(Vb + ((size_t)rv << 11) + kt * 32 + cv, Vl + base);
        }
        __syncthreads();
        f32x4 s[2];
        s[0] = (f32x4){0.f, 0.f, 0.f, 0.f};
        s[1] = (f32x4){0.f, 0.f, 0.f, 0.f};
        __builtin_amdgcn_s_setprio(1);
#pragma unroll
        for (int kk = 0; kk < 8; ++kk) {
#pragma unroll
            for (int nj = 0; nj < 2; ++nj) {
                f16x8 bk = *(const f16x8*)&Kl[(nj * 16 + lr) * 256 +
                                              ((kk * 32 + lg * 8) ^ kswz)];
                s[nj] = __builtin_amdgcn_mfma_f32_16x16x32_f16(aq[kk], bk, s[nj], 0, 0, 0);
            }
        }
        __builtin_amdgcn_s_setprio(0);
#pragma unroll
        for (int i = 0; i < 4; ++i) {
            int row = rowb + i;
#pragma unroll
            for (int nj = 0; nj < 2; ++nj) {
                int col = kt * 32 + nj * 16 + lr;
                float pv = (col <= row) ? exp2f(s[nj][i] - CEXP) * inv[i] : 0.f;
                Ps[wave][lg * 4 + i][nj * 16 + lr] = (f16)pv;
            }
        }
        // wide P store: wave writes its 16 rows x 32 cols from Ps (f16->f32)
        {
            int rr = lane >> 2;
            int cc = (lane & 3) * 8;
            f16x8 ph = *(const f16x8*)&Ps[wave][rr][cc];
            int row = q0 + wave * 16 + rr;
            float* dst = Pb + (size_t)row * SEQ + kt * 32 + cc;
            f32x4 lo = {(float)ph[0], (float)ph[1], (float)ph[2], (float)ph[3]};
            f32x4 hi = {(float)ph[4], (float)ph[5], (float)ph[6], (float)ph[7]};
            *(f32x4*)dst = lo;
            *(f32x4*)(dst + 4) = hi;
        }
        // PV accumulate (single K=32 chunk)
        __builtin_amdgcn_s_setprio(1);
        {
            f16x8 pa = *(const f16x8*)&Ps[wave][lr][lg * 8];
#pragma unroll
            for (int n = 0; n < 16; ++n) {
                f16x8 bv = *(const f16x8*)&Vl[(n * 16 + lr) * 32 + ((lg * 8) ^ vswz)];
                o[n] = __builtin_amdgcn_mfma_f32_16x16x32_f16(pa, bv, o[n], 0, 0, 0);
            }
        }
        __builtin_amdgcn_s_setprio(0);
    }

    // zero-fill strictly-masked P region for these 64 q rows
    int kstart = (qb + 1) * 64;
    if (kstart < SEQ) {
        f32x4 z = (f32x4){0.f, 0.f, 0.f, 0.f};
        for (int r = 0; r < 64; ++r) {
            float* rp = Pb + (size_t)(q0 + r) * SEQ;
            for (int c = kstart + tid * 4; c < SEQ; c += 1024)
                *(f32x4*)(rp + c) = z;
        }
    }

    // write O (f16) to [b, s, h*HD + d]
#pragma unroll
    for (int n = 0; n < 16; ++n) {
#pragma unroll
        for (int i = 0; i < 4; ++i) {
            int row = rowb + i;
            int d = n * 16 + lr;
            Oh[((size_t)b * SEQ + row) * DM + h * HD + d] = (f16)o[n][i];
        }
    }
}

// ---------------------------------------------------------------------------
extern "C" void kernel_launch(void* const* d_in, const int* in_sizes, int n_in,
                              void* d_out, int out_size, void* d_ws, size_t ws_size,
                              hipStream_t stream) {
    const float* x  = (const float*)d_in[0];
    const float* Wq = (const float*)d_in[1];
    const float* bq = (const float*)d_in[2];
    const float* Wk = (const float*)d_in[3];
    const float* bk = (const float*)d_in[4];
    const float* Wv = (const float*)d_in[5];
    const float* bv = (const float*)d_in[6];
    const float* Wo = (const float*)d_in[7];
    const float* bo = (const float*)d_in[8];

    float* out  = (float*)d_out;
    float* Pout = out + (size_t)MT * DM;          // attn_probs region (256MB)

    // f16 scratch for x and Wq/Wk/Wv parked inside the (not yet written) P
    // region of d_out; they are dead before k_attn overwrites that region.
    f16* xh  = (f16*)Pout;                         // 8388608 f16
    f16* Wqh = xh + (size_t)MT * DM;               // 4194304 f16 each
    f16* Wkh = Wqh + (size_t)DM * DM;
    f16* Wvh = Wkh + (size_t)DM * DM;

    // persistent f16 scratch in ws (must survive into/through k_attn)
    f16* ws16 = (f16*)d_ws;
    f16* Woh = ws16;                               // 4194304
    f16* Qh  = Woh + (size_t)DM * DM;              // 8388608
    f16* Kh  = Qh + (size_t)8388608;               // [b,h,s,d] = 8388608
    f16* Vth = Kh + (size_t)8388608;               // [b,h,d,s] = 8388608
    f16* Oh  = Vth + (size_t)8388608;              // [b,s,D]   = 8388608
    if (ws_size < (size_t)(4194304 + 4 * 8388608) * sizeof(f16)) return;

    // conversions
    k_cvt<<<2048, 256, 0, stream>>>(x, xh, MT * DM);
    k_cvt<<<1024, 256, 0, stream>>>(Wq, Wqh, DM * DM);
    k_cvt<<<1024, 256, 0, stream>>>(Wk, Wkh, DM * DM);
    k_cvt<<<1024, 256, 0, stream>>>(Wv, Wvh, DM * DM);
    k_cvt<<<1024, 256, 0, stream>>>(Wo, Woh, DM * DM);

    // QKV projections
    dim3 g1(DM / 128, MT / 128, 3);
    k_proj_qkv<<<g1, 256, 0, stream>>>(xh, Wqh, Wkh, Wvh, bq, bk, bv, Qh, Kh, Vth);

    // fused causal attention + P materialization (1D balanced grid)
    k_attn<<<dim3(512), 256, 0, stream>>>(Qh, Kh, Vth, Pout, Oh);

    // output projection
    dim3 g3(DM / 128, MT / 128, 1);
    k_proj_o<<<g3, 256, 0, stream>>>(Oh, Woh, bo, out);
}

// Round 4
// 397.065 us; speedup vs baseline: 1.3874x; 1.3874x over previous
//
#include <hip/hip_runtime.h>
#include <cstdint>
#include <cstddef>

typedef _Float16 f16;
typedef __attribute__((ext_vector_type(4))) _Float16 f16x4;
typedef __attribute__((ext_vector_type(8))) _Float16 f16x8;
typedef __attribute__((ext_vector_type(4))) float f32x4;

#define NB 2
#define SEQ 2048
#define DM 2048
#define NH 8
#define HD 256
#define MT (NB * SEQ)   // 4096

// S*scaling in log2 units: Q pre-scaled by 0.0625*log2(e); exp2 offset 16*log2(e)
#define QSCALE 0.09016844f
#define CEXP   23.08312065f

// ---------------------------------------------------------------------------
// global -> LDS direct copy, 16B per lane. LDS dest must be wave-uniform base.
__device__ __forceinline__ void gload16(const f16* g, f16* l) {
    __builtin_amdgcn_global_load_lds(
        (const __attribute__((address_space(1))) uint32_t*)(const void*)g,
        (__attribute__((address_space(3))) uint32_t*)(void*)l,
        16, 0, 0);
}

// ---------------------------------------------------------------------------
// f32 -> f16 conversion (vectorized, grid-stride)
__global__ __launch_bounds__(256) void k_cvt(const float* __restrict__ src,
                                             f16* __restrict__ dst, int n) {
    for (int i = (blockIdx.x * blockDim.x + threadIdx.x) * 4; i < n;
         i += gridDim.x * blockDim.x * 4) {
        f32x4 v = *(const f32x4*)(src + i);
        f16x4 h;
        h[0] = (f16)v[0]; h[1] = (f16)v[1]; h[2] = (f16)v[2]; h[3] = (f16)v[3];
        *(f16x4*)(dst + i) = h;
    }
}

// ---------------------------------------------------------------------------
// 128x128 tile GEMM core (m97 structure): C = A[M,K] * B[N,K]^T
__device__ __forceinline__ void gemm128_core(const f16* __restrict__ A,
                                             const f16* __restrict__ B,
                                             int m0, int n0,
                                             f16* As, f16* Bs,
                                             f32x4 acc[4][4]) {
    const int tid  = threadIdx.x;
    const int wave = tid >> 6, lane = tid & 63;
    const int wr = (wave >> 1) << 6, wc = (wave & 1) << 6;
    const int lr = lane & 15;            // row within 16
    const int lk = (lane >> 4) << 3;     // k elem offset (0,8,16,24)

    for (int k0 = 0; k0 < DM; k0 += 32) {
        __syncthreads();
#pragma unroll
        for (int j = 0; j < 2; ++j) {
            int base = (j * 4 + wave) << 9;          // 512 elems per wave-issue
            int flat = base + (lane << 3);
            int r = flat >> 5, c = flat & 31;
            gload16(A + (size_t)(m0 + r) * DM + k0 + c, As + base);
            gload16(B + (size_t)(n0 + r) * DM + k0 + c, Bs + base);
        }
        __syncthreads();
        f16x8 af[4], bf[4];
#pragma unroll
        for (int mi = 0; mi < 4; ++mi)
            af[mi] = *(const f16x8*)&As[(wr + mi * 16 + lr) * 32 + lk];
#pragma unroll
        for (int nj = 0; nj < 4; ++nj)
            bf[nj] = *(const f16x8*)&Bs[(wc + nj * 16 + lr) * 32 + lk];
        __builtin_amdgcn_s_setprio(1);
#pragma unroll
        for (int mi = 0; mi < 4; ++mi)
#pragma unroll
            for (int nj = 0; nj < 4; ++nj)
                acc[mi][nj] = __builtin_amdgcn_mfma_f32_16x16x32_f16(
                    af[mi], bf[nj], acc[mi][nj], 0, 0, 0);
        __builtin_amdgcn_s_setprio(0);
    }
}

// ---------------------------------------------------------------------------
// QKV projection: y = x @ W^T + b ; Q scaled by QSCALE; Q,K -> [b,h,s,d], V -> [b,h,d,s]
__global__ __launch_bounds__(256) void k_proj_qkv(
    const f16* __restrict__ xh, const f16* __restrict__ Wq,
    const f16* __restrict__ Wk, const f16* __restrict__ Wv,
    const float* __restrict__ bq, const float* __restrict__ bk,
    const float* __restrict__ bv,
    f16* __restrict__ Qh, f16* __restrict__ Kh, f16* __restrict__ Vth) {
    __shared__ __align__(16) f16 As[128 * 32];
    __shared__ __align__(16) f16 Bs[128 * 32];
    const int mode = blockIdx.z;
    const f16* W = (mode == 0) ? Wq : (mode == 1) ? Wk : Wv;
    const float* bias = (mode == 0) ? bq : (mode == 1) ? bk : bv;

    const int m0 = blockIdx.y * 128, n0 = blockIdx.x * 128;
    f32x4 acc[4][4];
#pragma unroll
    for (int mi = 0; mi < 4; ++mi)
#pragma unroll
        for (int nj = 0; nj < 4; ++nj) acc[mi][nj] = (f32x4){0.f, 0.f, 0.f, 0.f};

    gemm128_core(xh, W, m0, n0, As, Bs, acc);

    const int lane = threadIdx.x & 63, wave = threadIdx.x >> 6;
    const int wr = (wave >> 1) << 6, wc = (wave & 1) << 6;
    const int lr = lane & 15, lg = lane >> 4;
#pragma unroll
    for (int nj = 0; nj < 4; ++nj) {
        int n = n0 + wc + nj * 16 + lr;
        float bb = bias[n];
        int h = n >> 8, d = n & 255;
#pragma unroll
        for (int mi = 0; mi < 4; ++mi) {
#pragma unroll
            for (int i = 0; i < 4; ++i) {
                int m = m0 + wr + mi * 16 + lg * 4 + i;
                int b = m >> 11, s = m & 2047;
                float v = acc[mi][nj][i] + bb;
                size_t bh = (size_t)(b * NH + h);
                if (mode == 0)
                    Qh[((bh * SEQ + s) << 8) + d] = (f16)(v * QSCALE);
                else if (mode == 1)
                    Kh[((bh * SEQ + s) << 8) + d] = (f16)v;
                else
                    Vth[((bh * HD + d) << 11) + s] = (f16)v;
            }
        }
    }
}

// ---------------------------------------------------------------------------
// Output projection: out = O @ Wo^T + bo  (f32 out)
__global__ __launch_bounds__(256) void k_proj_o(
    const f16* __restrict__ Oh, const f16* __restrict__ Wo,
    const float* __restrict__ bo, float* __restrict__ out) {
    __shared__ __align__(16) f16 As[128 * 32];
    __shared__ __align__(16) f16 Bs[128 * 32];
    const int m0 = blockIdx.y * 128, n0 = blockIdx.x * 128;
    f32x4 acc[4][4];
#pragma unroll
    for (int mi = 0; mi < 4; ++mi)
#pragma unroll
        for (int nj = 0; nj < 4; ++nj) acc[mi][nj] = (f32x4){0.f, 0.f, 0.f, 0.f};

    gemm128_core(Oh, Wo, m0, n0, As, Bs, acc);

    const int lane = threadIdx.x & 63, wave = threadIdx.x >> 6;
    const int wr = (wave >> 1) << 6, wc = (wave & 1) << 6;
    const int lr = lane & 15, lg = lane >> 4;
#pragma unroll
    for (int nj = 0; nj < 4; ++nj) {
        int n = n0 + wc + nj * 16 + lr;
        float bb = bo[n];
#pragma unroll
        for (int mi = 0; mi < 4; ++mi) {
#pragma unroll
            for (int i = 0; i < 4; ++i) {
                int m = m0 + wr + mi * 16 + lg * 4 + i;
                out[(size_t)m * DM + n] = acc[mi][nj][i] + bb;
            }
        }
    }
}

// ---------------------------------------------------------------------------
// K-tile stage: 64 rows x 256 cols, row-XOR-swizzled via pre-swizzled source.
__device__ __forceinline__ void stageK(const f16* __restrict__ Kb, int kt,
                                       f16* buf, int wave, int lane) {
#pragma unroll
    for (int j = 0; j < 8; ++j) {
        int base = (j * 4 + wave) << 9;
        int flat = base + (lane << 3);
        int r = flat >> 8;
        int c = (flat & 255) ^ ((r & 7) << 3);
        gload16(Kb + (size_t)(kt * 64 + r) * HD + c, buf + base);
    }
}
// V-tile stage: [256][64] transposed layout, swizzled.
__device__ __forceinline__ void stageV(const f16* __restrict__ Vb, int kt,
                                       f16* buf, int wave, int lane) {
#pragma unroll
    for (int j = 0; j < 8; ++j) {
        int base = (j * 4 + wave) << 9;
        int flat = base + (lane << 3);
        int rv = flat >> 6;
        int cv = (flat & 63) ^ ((rv & 3) << 3);
        gload16(Vb + ((size_t)rv << 11) + kt * 64 + cv, buf + base);
    }
}

// ---------------------------------------------------------------------------
// Fused causal attention. KVBLK=64, QBLK=64, 4 waves.
// XCD-locality mapping: xcd = bid&7 owns 2 (b,h) groups (K+V = 4MB = L2/XCD);
// per-CU complementary qb pairing balances work.
// Fixed-max softmax (exact; exp2 args bounded). Pass A: 2-phase K double-buffer.
// Pass B: counted-vmcnt pipeline (prefetch K[t+1] during PV; V hidden under QK^T).
__global__ __launch_bounds__(256, 2) void k_attn(
    const f16* __restrict__ Qh, const f16* __restrict__ Kh,
    const f16* __restrict__ Vth, float* __restrict__ P,
    f16* __restrict__ Oh) {
    __shared__ __align__(16) f16 B0[64 * 256];     // 32KB: K (both passes)
    __shared__ __align__(16) f16 B1[64 * 256];     // 32KB: K dbuf (A) / V (B)
    __shared__ __align__(16) f16 Ps[4][16][72];    // per-wave P tile (pad 8)

    const int bid = blockIdx.x;
    const int xcd = bid & 7;
    const int slot = bid >> 3;          // arrival order within XCD (0..63)
    const int psel = slot >> 5;         // which of the 2 (b,h) groups
    const int s5 = slot & 31;
    const int qb = psel ? s5 : (31 - s5);   // CU c gets qb=31-c and qb=c
    const int bhid = xcd * 2 + psel;    // 0..15
    const int b = bhid >> 3, h = bhid & 7;

    const int q0 = qb * 64;
    const int tid = threadIdx.x, wave = tid >> 6, lane = tid & 63;
    const int lr = lane & 15, lg = lane >> 4;
    const size_t bh = (size_t)bhid;
    const f16* Qb = Qh + (bh << 19);
    const f16* Kb = Kh + (bh << 19);
    const f16* Vb = Vth + (bh << 19);
    float* Pb = P + (bh << 22);

    const int kswz = (lr & 7) << 3;   // K read-side XOR (elem units)
    const int vswz = (lr & 3) << 3;   // V read-side XOR

    // Q fragments in registers (16 q-rows x 256 d per wave)
    f16x8 aq[8];
    {
        const f16* qrow = Qb + (size_t)(q0 + wave * 16 + lr) * HD + lg * 8;
#pragma unroll
        for (int kk = 0; kk < 8; ++kk) aq[kk] = *(const f16x8*)(qrow + kk * 32);
    }

    const int rowb = q0 + wave * 16 + lg * 4;  // +i gives absolute q row
    const int nt = qb + 1;                     // 64-wide k tiles

    float psum[4] = {0.f, 0.f, 0.f, 0.f};

    // ---------------- PASS A: row sums (fixed max), 2-phase K dbuf ----------
    stageK(Kb, 0, B0, wave, lane);
    __syncthreads();                           // drains vmcnt: K[0] resident
    for (int kt = 0; kt < nt; ++kt) {
        f16* cur = (kt & 1) ? B1 : B0;
        f16* nxt = (kt & 1) ? B0 : B1;
        if (kt + 1 < nt) stageK(Kb, kt + 1, nxt, wave, lane);
        f32x4 s[4];
#pragma unroll
        for (int nj = 0; nj < 4; ++nj) s[nj] = (f32x4){0.f, 0.f, 0.f, 0.f};
        __builtin_amdgcn_s_setprio(1);
#pragma unroll
        for (int kk = 0; kk < 8; ++kk) {
#pragma unroll
            for (int nj = 0; nj < 4; ++nj) {
                f16x8 bk = *(const f16x8*)&cur[(nj * 16 + lr) * 256 +
                                               ((kk * 32 + lg * 8) ^ kswz)];
                s[nj] = __builtin_amdgcn_mfma_f32_16x16x32_f16(aq[kk], bk, s[nj], 0, 0, 0);
            }
        }
        __builtin_amdgcn_s_setprio(0);
        const int colb = kt * 64 + lr;
#pragma unroll
        for (int i = 0; i < 4; ++i) {
            int row = rowb + i;
#pragma unroll
            for (int nj = 0; nj < 4; ++nj)
                psum[i] += (colb + nj * 16 <= row) ? exp2f(s[nj][i] - CEXP) : 0.f;
        }
        __syncthreads();   // vmcnt(0)+lgkm drain: nxt landed, cur reads done
    }

    float inv[4];
#pragma unroll
    for (int i = 0; i < 4; ++i) {
        float l = psum[i];
        l += __shfl_xor(l, 1);
        l += __shfl_xor(l, 2);
        l += __shfl_xor(l, 4);
        l += __shfl_xor(l, 8);
        inv[i] = 1.f / l;
    }

    f32x4 o[16];
#pragma unroll
    for (int n = 0; n < 16; ++n) o[n] = (f32x4){0.f, 0.f, 0.f, 0.f};

    // ---------------- PASS B: pipelined P write + O accumulate --------------
    stageK(Kb, 0, B0, wave, lane);             // prefetch K[0] (in flight)
    for (int kt = 0; kt < nt; ++kt) {
        stageV(Vb, kt, B1, wave, lane);        // V flies under QK^T
        asm volatile("s_waitcnt vmcnt(8)" ::: "memory");  // K[kt] (+prev stores) landed
        __builtin_amdgcn_s_barrier();
        __builtin_amdgcn_sched_barrier(0);

        f32x4 s[4];
#pragma unroll
        for (int nj = 0; nj < 4; ++nj) s[nj] = (f32x4){0.f, 0.f, 0.f, 0.f};
        __builtin_amdgcn_s_setprio(1);
#pragma unroll
        for (int kk = 0; kk < 8; ++kk) {
#pragma unroll
            for (int nj = 0; nj < 4; ++nj) {
                f16x8 bk = *(const f16x8*)&B0[(nj * 16 + lr) * 256 +
                                              ((kk * 32 + lg * 8) ^ kswz)];
                s[nj] = __builtin_amdgcn_mfma_f32_16x16x32_f16(aq[kk], bk, s[nj], 0, 0, 0);
            }
        }
        __builtin_amdgcn_s_setprio(0);
#pragma unroll
        for (int i = 0; i < 4; ++i) {
            int row = rowb + i;
#pragma unroll
            for (int nj = 0; nj < 4; ++nj) {
                int col = kt * 64 + nj * 16 + lr;
                float pv = (col <= row) ? exp2f(s[nj][i] - CEXP) * inv[i] : 0.f;
                Ps[wave][lg * 4 + i][nj * 16 + lr] = (f16)pv;
            }
        }
        asm volatile("s_waitcnt vmcnt(0)" ::: "memory");  // V landed
        __builtin_amdgcn_s_barrier();                     // + all B0 reads done
        __builtin_amdgcn_sched_barrier(0);

        if (kt + 1 < nt) stageK(Kb, kt + 1, B0, wave, lane);  // flies under PV

        // wide P store: wave writes its 16 rows x 64 cols from Ps (f16->f32)
#pragma unroll
        for (int h2 = 0; h2 < 2; ++h2) {
            int rr = h2 * 8 + (lane >> 3);
            int cc = (lane & 7) * 8;
            f16x8 ph = *(const f16x8*)&Ps[wave][rr][cc];
            int row = q0 + wave * 16 + rr;
            float* dst = Pb + (size_t)row * SEQ + kt * 64 + cc;
            f32x4 lo = {(float)ph[0], (float)ph[1], (float)ph[2], (float)ph[3]};
            f32x4 hi = {(float)ph[4], (float)ph[5], (float)ph[6], (float)ph[7]};
            *(f32x4*)dst = lo;
            *(f32x4*)(dst + 4) = hi;
        }

        // PV accumulate (reads B1 + Ps)
        __builtin_amdgcn_s_setprio(1);
#pragma unroll
        for (int kk2 = 0; kk2 < 2; ++kk2) {
            f16x8 pa = *(const f16x8*)&Ps[wave][lr][kk2 * 32 + lg * 8];
#pragma unroll
            for (int n = 0; n < 16; ++n) {
                f16x8 bv = *(const f16x8*)&B1[(n * 16 + lr) * 64 +
                                              ((kk2 * 32 + lg * 8) ^ vswz)];
                o[n] = __builtin_amdgcn_mfma_f32_16x16x32_f16(pa, bv, o[n], 0, 0, 0);
            }
        }
        __builtin_amdgcn_s_setprio(0);
        asm volatile("" ::: "memory");
        __builtin_amdgcn_s_barrier();          // B1 reads done before next V stage
        __builtin_amdgcn_sched_barrier(0);
    }

    // zero-fill strictly-masked P region for these 64 q rows
    int kstart = (qb + 1) * 64;
    if (kstart < SEQ) {
        f32x4 z = (f32x4){0.f, 0.f, 0.f, 0.f};
        for (int r = 0; r < 64; ++r) {
            float* rp = Pb + (size_t)(q0 + r) * SEQ;
            for (int c = kstart + tid * 4; c < SEQ; c += 1024)
                *(f32x4*)(rp + c) = z;
        }
    }

    // write O (f16) to [b, s, h*HD + d]
#pragma unroll
    for (int n = 0; n < 16; ++n) {
#pragma unroll
        for (int i = 0; i < 4; ++i) {
            int row = rowb + i;
            int d = n * 16 + lr;
            Oh[((size_t)b * SEQ + row) * DM + h * HD + d] = (f16)o[n][i];
        }
    }
}

// ---------------------------------------------------------------------------
extern "C" void kernel_launch(void* const* d_in, const int* in_sizes, int n_in,
                              void* d_out, int out_size, void* d_ws, size_t ws_size,
                              hipStream_t stream) {
    const float* x  = (const float*)d_in[0];
    const float* Wq = (const float*)d_in[1];
    const float* bq = (const float*)d_in[2];
    const float* Wk = (const float*)d_in[3];
    const float* bk = (const float*)d_in[4];
    const float* Wv = (const float*)d_in[5];
    const float* bv = (const float*)d_in[6];
    const float* Wo = (const float*)d_in[7];
    const float* bo = (const float*)d_in[8];

    float* out  = (float*)d_out;
    float* Pout = out + (size_t)MT * DM;          // attn_probs region (256MB)

    // f16 scratch for x and Wq/Wk/Wv parked inside the (not yet written) P
    // region of d_out; they are dead before k_attn overwrites that region.
    f16* xh  = (f16*)Pout;                         // 8388608 f16
    f16* Wqh = xh + (size_t)MT * DM;               // 4194304 f16 each
    f16* Wkh = Wqh + (size_t)DM * DM;
    f16* Wvh = Wkh + (size_t)DM * DM;

    // persistent f16 scratch in ws (must survive into/through k_attn)
    f16* ws16 = (f16*)d_ws;
    f16* Woh = ws16;                               // 4194304
    f16* Qh  = Woh + (size_t)DM * DM;              // 8388608
    f16* Kh  = Qh + (size_t)8388608;               // [b,h,s,d] = 8388608
    f16* Vth = Kh + (size_t)8388608;               // [b,h,d,s] = 8388608
    f16* Oh  = Vth + (size_t)8388608;              // [b,s,D]   = 8388608
    if (ws_size < (size_t)(4194304 + 4 * 8388608) * sizeof(f16)) return;

    // conversions
    k_cvt<<<2048, 256, 0, stream>>>(x, xh, MT * DM);
    k_cvt<<<1024, 256, 0, stream>>>(Wq, Wqh, DM * DM);
    k_cvt<<<1024, 256, 0, stream>>>(Wk, Wkh, DM * DM);
    k_cvt<<<1024, 256, 0, stream>>>(Wv, Wvh, DM * DM);
    k_cvt<<<1024, 256, 0, stream>>>(Wo, Woh, DM * DM);

    // QKV projections
    dim3 g1(DM / 128, MT / 128, 3);
    k_proj_qkv<<<g1, 256, 0, stream>>>(xh, Wqh, Wkh, Wvh, bq, bk, bv, Qh, Kh, Vth);

    // fused causal attention + P materialization (XCD-locality 1D grid)
    k_attn<<<dim3(512), 256, 0, stream>>>(Qh, Kh, Vth, Pout, Oh);

    // output projection
    dim3 g3(DM / 128, MT / 128, 1);
    k_proj_o<<<g3, 256, 0, stream>>>(Oh, Woh, bo, out);
}

// Round 5
// 376.729 us; speedup vs baseline: 1.4623x; 1.0540x over previous
//
#include <hip/hip_runtime.h>
#include <cstdint>
#include <cstddef>

typedef _Float16 f16;
typedef __attribute__((ext_vector_type(4))) _Float16 f16x4;
typedef __attribute__((ext_vector_type(8))) _Float16 f16x8;
typedef __attribute__((ext_vector_type(4))) float f32x4;

#define NB 2
#define SEQ 2048
#define DM 2048
#define NH 8
#define HD 256
#define MT (NB * SEQ)   // 4096

// S*scaling in log2 units: Q pre-scaled by 0.0625*log2(e); exp2 offset 16*log2(e)
#define QSCALE 0.09016844f
#define CEXP   23.08312065f

// ---------------------------------------------------------------------------
// global -> LDS direct copy, 16B per lane. LDS dest must be wave-uniform base.
__device__ __forceinline__ void gload16(const f16* g, f16* l) {
    __builtin_amdgcn_global_load_lds(
        (const __attribute__((address_space(1))) uint32_t*)(const void*)g,
        (__attribute__((address_space(3))) uint32_t*)(void*)l,
        16, 0, 0);
}

// ---------------------------------------------------------------------------
// f32 -> f16 conversion (vectorized, grid-stride)
__global__ __launch_bounds__(256) void k_cvt(const float* __restrict__ src,
                                             f16* __restrict__ dst, int n) {
    for (int i = (blockIdx.x * blockDim.x + threadIdx.x) * 4; i < n;
         i += gridDim.x * blockDim.x * 4) {
        f32x4 v = *(const f32x4*)(src + i);
        f16x4 h;
        h[0] = (f16)v[0]; h[1] = (f16)v[1]; h[2] = (f16)v[2]; h[3] = (f16)v[3];
        *(f16x4*)(dst + i) = h;
    }
}

// ===========================================================================
// 256x128 tile GEMM, BK=64, 8 waves (512 thr), 3-buffer deep pipeline.
// Wave (wm=wave>>1 in [0,4), wn=wave&1 in [0,2)) owns a 64x64 output sub-tile
// = 4x4 frags of 16x16x32 f16. LDS XOR-swizzled (elem ^= (row&7)<<3) via
// pre-swizzled global source; staging runs 2 K-tiles ahead; per-tile sync is
// s_waitcnt vmcnt(6) + one raw s_barrier (never drains the prefetch).
// ===========================================================================

// stage one K-tile: A-panel [256][64] (4 issues) + B-panel [128][64] (2 issues)
__device__ __forceinline__ void stage6(const f16* __restrict__ A,
                                       const f16* __restrict__ B,
                                       int m0, int n0, int k0,
                                       f16* AL, f16* BL, int tid) {
#pragma unroll
    for (int j = 0; j < 4; ++j) {
        int flat = j * 4096 + tid * 8;
        int r = flat >> 6, c = flat & 63;
        int cs = c ^ ((r & 7) << 3);
        gload16(A + (size_t)(m0 + r) * DM + k0 + cs,
                AL + j * 4096 + (tid >> 6) * 512);
    }
#pragma unroll
    for (int j = 0; j < 2; ++j) {
        int flat = j * 4096 + tid * 8;
        int r = flat >> 6, c = flat & 63;
        int cs = c ^ ((r & 7) << 3);
        gload16(B + (size_t)(n0 + r) * DM + k0 + cs,
                BL + j * 4096 + (tid >> 6) * 512);
    }
}

__device__ __forceinline__ f16x8 rdfrag(const f16* buf, int rowbase, int lr,
                                        int lg, int kk) {
    int row = rowbase + lr;
    int c = (kk * 32 + lg * 8) ^ ((lr & 7) << 3);
    return *(const f16x8*)&buf[row * 64 + c];
}

__device__ __forceinline__ void gemm256x128_core(const f16* __restrict__ A,
                                                 const f16* __restrict__ B,
                                                 int m0, int n0,
                                                 f16* AL, f16* BL,
                                                 f32x4 acc[4][4]) {
    const int tid = threadIdx.x, wave = tid >> 6, lane = tid & 63;
    const int wm = wave >> 1, wn = wave & 1;
    const int lr = lane & 15, lg = lane >> 4;
    const int nt = DM / 64;

    // prologue: stage K-tiles 0 and 1 (12 loads in flight)
    stage6(A, B, m0, n0, 0, AL, BL, tid);
    stage6(A, B, m0, n0, 64, AL + 16384, BL + 8192, tid);

    for (int kt = 0; kt < nt; ++kt) {
        // all-but-newest-6 retired => K-tile kt fully in LDS (in-order vmcnt)
        if (kt + 1 < nt) asm volatile("s_waitcnt vmcnt(6)" ::: "memory");
        else             asm volatile("s_waitcnt vmcnt(0)" ::: "memory");
        __builtin_amdgcn_s_barrier();
        __builtin_amdgcn_sched_barrier(0);

        const f16* Ab = AL + (kt % 3) * 16384;
        const f16* Bb = BL + (kt % 3) * 8192;
        const int arb = wm * 64, brb = wn * 64;

        // ---- ph0: A-low + B-low frags, stage tile kt+2, MFMA quad(0,0) ----
        f16x8 a0[2][2], b0[2][2];
#pragma unroll
        for (int mf = 0; mf < 2; ++mf)
#pragma unroll
            for (int kk = 0; kk < 2; ++kk)
                a0[mf][kk] = rdfrag(Ab, arb + mf * 16, lr, lg, kk);
#pragma unroll
        for (int nf = 0; nf < 2; ++nf)
#pragma unroll
            for (int kk = 0; kk < 2; ++kk)
                b0[nf][kk] = rdfrag(Bb, brb + nf * 16, lr, lg, kk);

        if (kt + 2 < nt)
            stage6(A, B, m0, n0, (kt + 2) * 64,
                   AL + ((kt + 2) % 3) * 16384, BL + ((kt + 2) % 3) * 8192, tid);

        __builtin_amdgcn_s_setprio(1);
#pragma unroll
        for (int mi = 0; mi < 2; ++mi)
#pragma unroll
            for (int nj = 0; nj < 2; ++nj)
#pragma unroll
                for (int kk = 0; kk < 2; ++kk)
                    acc[mi][nj] = __builtin_amdgcn_mfma_f32_16x16x32_f16(
                        a0[mi][kk], b0[nj][kk], acc[mi][nj], 0, 0, 0);
        __builtin_amdgcn_s_setprio(0);

        // ---- ph1: B-high frags, MFMA quad(0,1) ----
        f16x8 b1[2][2];
#pragma unroll
        for (int nf = 0; nf < 2; ++nf)
#pragma unroll
            for (int kk = 0; kk < 2; ++kk)
                b1[nf][kk] = rdfrag(Bb, brb + 32 + nf * 16, lr, lg, kk);
        __builtin_amdgcn_s_setprio(1);
#pragma unroll
        for (int mi = 0; mi < 2; ++mi)
#pragma unroll
            for (int nj = 0; nj < 2; ++nj)
#pragma unroll
                for (int kk = 0; kk < 2; ++kk)
                    acc[mi][nj + 2] = __builtin_amdgcn_mfma_f32_16x16x32_f16(
                        a0[mi][kk], b1[nj][kk], acc[mi][nj + 2], 0, 0, 0);
        __builtin_amdgcn_s_setprio(0);

        // ---- ph2: A-high frags, MFMA quad(1,0) ----
        f16x8 a1[2][2];
#pragma unroll
        for (int mf = 0; mf < 2; ++mf)
#pragma unroll
            for (int kk = 0; kk < 2; ++kk)
                a1[mf][kk] = rdfrag(Ab, arb + 32 + mf * 16, lr, lg, kk);
        __builtin_amdgcn_s_setprio(1);
#pragma unroll
        for (int mi = 0; mi < 2; ++mi)
#pragma unroll
            for (int nj = 0; nj < 2; ++nj)
#pragma unroll
                for (int kk = 0; kk < 2; ++kk)
                    acc[mi + 2][nj] = __builtin_amdgcn_mfma_f32_16x16x32_f16(
                        a1[mi][kk], b0[nj][kk], acc[mi + 2][nj], 0, 0, 0);
        __builtin_amdgcn_s_setprio(0);

        // ---- ph3: MFMA quad(1,1) ----
        __builtin_amdgcn_s_setprio(1);
#pragma unroll
        for (int mi = 0; mi < 2; ++mi)
#pragma unroll
            for (int nj = 0; nj < 2; ++nj)
#pragma unroll
                for (int kk = 0; kk < 2; ++kk)
                    acc[mi + 2][nj + 2] = __builtin_amdgcn_mfma_f32_16x16x32_f16(
                        a1[mi][kk], b1[nj][kk], acc[mi + 2][nj + 2], 0, 0, 0);
        __builtin_amdgcn_s_setprio(0);
    }
}

// ---------------------------------------------------------------------------
// QKV projection: y = x @ W^T + b ; Q scaled by QSCALE; Q,K -> [b,h,s,d], V -> [b,h,d,s]
__global__ __launch_bounds__(512, 1) void k_proj_qkv(
    const f16* __restrict__ xh, const f16* __restrict__ Wq,
    const f16* __restrict__ Wk, const f16* __restrict__ Wv,
    const float* __restrict__ bq, const float* __restrict__ bk,
    const float* __restrict__ bv,
    f16* __restrict__ Qh, f16* __restrict__ Kh, f16* __restrict__ Vth) {
    __shared__ __align__(16) f16 AL[3 * 16384];   // 96KB
    __shared__ __align__(16) f16 BL[3 * 8192];    // 48KB
    const int mode = blockIdx.z;
    const f16* W = (mode == 0) ? Wq : (mode == 1) ? Wk : Wv;
    const float* bias = (mode == 0) ? bq : (mode == 1) ? bk : bv;

    const int m0 = blockIdx.y * 256, n0 = blockIdx.x * 128;
    f32x4 acc[4][4];
#pragma unroll
    for (int mi = 0; mi < 4; ++mi)
#pragma unroll
        for (int nj = 0; nj < 4; ++nj) acc[mi][nj] = (f32x4){0.f, 0.f, 0.f, 0.f};

    gemm256x128_core(xh, W, m0, n0, AL, BL, acc);

    const int lane = threadIdx.x & 63, wave = threadIdx.x >> 6;
    const int wm = wave >> 1, wn = wave & 1;
    const int lr = lane & 15, lg = lane >> 4;
#pragma unroll
    for (int nj = 0; nj < 4; ++nj) {
        int n = n0 + wn * 64 + nj * 16 + lr;
        float bb = bias[n];
        int h = n >> 8, d = n & 255;
#pragma unroll
        for (int mi = 0; mi < 4; ++mi) {
#pragma unroll
            for (int i = 0; i < 4; ++i) {
                int m = m0 + wm * 64 + mi * 16 + lg * 4 + i;
                int b = m >> 11, s = m & 2047;
                float v = acc[mi][nj][i] + bb;
                size_t bh = (size_t)(b * NH + h);
                if (mode == 0)
                    Qh[((bh * SEQ + s) << 8) + d] = (f16)(v * QSCALE);
                else if (mode == 1)
                    Kh[((bh * SEQ + s) << 8) + d] = (f16)v;
                else
                    Vth[((bh * HD + d) << 11) + s] = (f16)v;
            }
        }
    }
}

// ---------------------------------------------------------------------------
// Output projection: out = O @ Wo^T + bo  (f32 out)
__global__ __launch_bounds__(512, 1) void k_proj_o(
    const f16* __restrict__ Oh, const f16* __restrict__ Wo,
    const float* __restrict__ bo, float* __restrict__ out) {
    __shared__ __align__(16) f16 AL[3 * 16384];
    __shared__ __align__(16) f16 BL[3 * 8192];
    const int m0 = blockIdx.y * 256, n0 = blockIdx.x * 128;
    f32x4 acc[4][4];
#pragma unroll
    for (int mi = 0; mi < 4; ++mi)
#pragma unroll
        for (int nj = 0; nj < 4; ++nj) acc[mi][nj] = (f32x4){0.f, 0.f, 0.f, 0.f};

    gemm256x128_core(Oh, Wo, m0, n0, AL, BL, acc);

    const int lane = threadIdx.x & 63, wave = threadIdx.x >> 6;
    const int wm = wave >> 1, wn = wave & 1;
    const int lr = lane & 15, lg = lane >> 4;
#pragma unroll
    for (int nj = 0; nj < 4; ++nj) {
        int n = n0 + wn * 64 + nj * 16 + lr;
        float bb = bo[n];
#pragma unroll
        for (int mi = 0; mi < 4; ++mi) {
#pragma unroll
            for (int i = 0; i < 4; ++i) {
                int m = m0 + wm * 64 + mi * 16 + lg * 4 + i;
                out[(size_t)m * DM + n] = acc[mi][nj][i] + bb;
            }
        }
    }
}

// ---------------------------------------------------------------------------
// K-tile stage: 64 rows x 256 cols, row-XOR-swizzled via pre-swizzled source.
__device__ __forceinline__ void stageK(const f16* __restrict__ Kb, int kt,
                                       f16* buf, int wave, int lane) {
#pragma unroll
    for (int j = 0; j < 8; ++j) {
        int base = (j * 4 + wave) << 9;
        int flat = base + (lane << 3);
        int r = flat >> 8;
        int c = (flat & 255) ^ ((r & 7) << 3);
        gload16(Kb + (size_t)(kt * 64 + r) * HD + c, buf + base);
    }
}
// V-tile stage: [256][64] transposed layout, swizzled.
__device__ __forceinline__ void stageV(const f16* __restrict__ Vb, int kt,
                                       f16* buf, int wave, int lane) {
#pragma unroll
    for (int j = 0; j < 8; ++j) {
        int base = (j * 4 + wave) << 9;
        int flat = base + (lane << 3);
        int rv = flat >> 6;
        int cv = (flat & 63) ^ ((rv & 3) << 3);
        gload16(Vb + ((size_t)rv << 11) + kt * 64 + cv, buf + base);
    }
}

// ---------------------------------------------------------------------------
// Fused causal attention (unchanged from R3). KVBLK=64, QBLK=64, 4 waves.
__global__ __launch_bounds__(256, 2) void k_attn(
    const f16* __restrict__ Qh, const f16* __restrict__ Kh,
    const f16* __restrict__ Vth, float* __restrict__ P,
    f16* __restrict__ Oh) {
    __shared__ __align__(16) f16 B0[64 * 256];     // 32KB: K (both passes)
    __shared__ __align__(16) f16 B1[64 * 256];     // 32KB: K dbuf (A) / V (B)
    __shared__ __align__(16) f16 Ps[4][16][72];    // per-wave P tile (pad 8)

    const int bid = blockIdx.x;
    const int xcd = bid & 7;
    const int slot = bid >> 3;          // arrival order within XCD (0..63)
    const int psel = slot >> 5;         // which of the 2 (b,h) groups
    const int s5 = slot & 31;
    const int qb = psel ? s5 : (31 - s5);   // CU c gets qb=31-c and qb=c
    const int bhid = xcd * 2 + psel;    // 0..15
    const int b = bhid >> 3, h = bhid & 7;

    const int q0 = qb * 64;
    const int tid = threadIdx.x, wave = tid >> 6, lane = tid & 63;
    const int lr = lane & 15, lg = lane >> 4;
    const size_t bh = (size_t)bhid;
    const f16* Qb = Qh + (bh << 19);
    const f16* Kb = Kh + (bh << 19);
    const f16* Vb = Vth + (bh << 19);
    float* Pb = P + (bh << 22);

    const int kswz = (lr & 7) << 3;   // K read-side XOR (elem units)
    const int vswz = (lr & 3) << 3;   // V read-side XOR

    // Q fragments in registers (16 q-rows x 256 d per wave)
    f16x8 aq[8];
    {
        const f16* qrow = Qb + (size_t)(q0 + wave * 16 + lr) * HD + lg * 8;
#pragma unroll
        for (int kk = 0; kk < 8; ++kk) aq[kk] = *(const f16x8*)(qrow + kk * 32);
    }

    const int rowb = q0 + wave * 16 + lg * 4;  // +i gives absolute q row
    const int nt = qb + 1;                     // 64-wide k tiles

    float psum[4] = {0.f, 0.f, 0.f, 0.f};

    // ---------------- PASS A: row sums (fixed max), 2-phase K dbuf ----------
    stageK(Kb, 0, B0, wave, lane);
    __syncthreads();                           // drains vmcnt: K[0] resident
    for (int kt = 0; kt < nt; ++kt) {
        f16* cur = (kt & 1) ? B1 : B0;
        f16* nxt = (kt & 1) ? B0 : B1;
        if (kt + 1 < nt) stageK(Kb, kt + 1, nxt, wave, lane);
        f32x4 s[4];
#pragma unroll
        for (int nj = 0; nj < 4; ++nj) s[nj] = (f32x4){0.f, 0.f, 0.f, 0.f};
        __builtin_amdgcn_s_setprio(1);
#pragma unroll
        for (int kk = 0; kk < 8; ++kk) {
#pragma unroll
            for (int nj = 0; nj < 4; ++nj) {
                f16x8 bk = *(const f16x8*)&cur[(nj * 16 + lr) * 256 +
                                               ((kk * 32 + lg * 8) ^ kswz)];
                s[nj] = __builtin_amdgcn_mfma_f32_16x16x32_f16(aq[kk], bk, s[nj], 0, 0, 0);
            }
        }
        __builtin_amdgcn_s_setprio(0);
        const int colb = kt * 64 + lr;
#pragma unroll
        for (int i = 0; i < 4; ++i) {
            int row = rowb + i;
#pragma unroll
            for (int nj = 0; nj < 4; ++nj)
                psum[i] += (colb + nj * 16 <= row) ? exp2f(s[nj][i] - CEXP) : 0.f;
        }
        __syncthreads();   // vmcnt(0)+lgkm drain: nxt landed, cur reads done
    }

    float inv[4];
#pragma unroll
    for (int i = 0; i < 4; ++i) {
        float l = psum[i];
        l += __shfl_xor(l, 1);
        l += __shfl_xor(l, 2);
        l += __shfl_xor(l, 4);
        l += __shfl_xor(l, 8);
        inv[i] = 1.f / l;
    }

    f32x4 o[16];
#pragma unroll
    for (int n = 0; n < 16; ++n) o[n] = (f32x4){0.f, 0.f, 0.f, 0.f};

    // ---------------- PASS B: pipelined P write + O accumulate --------------
    stageK(Kb, 0, B0, wave, lane);             // prefetch K[0] (in flight)
    for (int kt = 0; kt < nt; ++kt) {
        stageV(Vb, kt, B1, wave, lane);        // V flies under QK^T
        asm volatile("s_waitcnt vmcnt(8)" ::: "memory");  // K[kt] (+prev stores) landed
        __builtin_amdgcn_s_barrier();
        __builtin_amdgcn_sched_barrier(0);

        f32x4 s[4];
#pragma unroll
        for (int nj = 0; nj < 4; ++nj) s[nj] = (f32x4){0.f, 0.f, 0.f, 0.f};
        __builtin_amdgcn_s_setprio(1);
#pragma unroll
        for (int kk = 0; kk < 8; ++kk) {
#pragma unroll
            for (int nj = 0; nj < 4; ++nj) {
                f16x8 bk = *(const f16x8*)&B0[(nj * 16 + lr) * 256 +
                                              ((kk * 32 + lg * 8) ^ kswz)];
                s[nj] = __builtin_amdgcn_mfma_f32_16x16x32_f16(aq[kk], bk, s[nj], 0, 0, 0);
            }
        }
        __builtin_amdgcn_s_setprio(0);
#pragma unroll
        for (int i = 0; i < 4; ++i) {
            int row = rowb + i;
#pragma unroll
            for (int nj = 0; nj < 4; ++nj) {
                int col = kt * 64 + nj * 16 + lr;
                float pv = (col <= row) ? exp2f(s[nj][i] - CEXP) * inv[i] : 0.f;
                Ps[wave][lg * 4 + i][nj * 16 + lr] = (f16)pv;
            }
        }
        asm volatile("s_waitcnt vmcnt(0)" ::: "memory");  // V landed
        __builtin_amdgcn_s_barrier();                     // + all B0 reads done
        __builtin_amdgcn_sched_barrier(0);

        if (kt + 1 < nt) stageK(Kb, kt + 1, B0, wave, lane);  // flies under PV

        // wide P store: wave writes its 16 rows x 64 cols from Ps (f16->f32)
#pragma unroll
        for (int h2 = 0; h2 < 2; ++h2) {
            int rr = h2 * 8 + (lane >> 3);
            int cc = (lane & 7) * 8;
            f16x8 ph = *(const f16x8*)&Ps[wave][rr][cc];
            int row = q0 + wave * 16 + rr;
            float* dst = Pb + (size_t)row * SEQ + kt * 64 + cc;
            f32x4 lo = {(float)ph[0], (float)ph[1], (float)ph[2], (float)ph[3]};
            f32x4 hi = {(float)ph[4], (float)ph[5], (float)ph[6], (float)ph[7]};
            *(f32x4*)dst = lo;
            *(f32x4*)(dst + 4) = hi;
        }

        // PV accumulate (reads B1 + Ps)
        __builtin_amdgcn_s_setprio(1);
#pragma unroll
        for (int kk2 = 0; kk2 < 2; ++kk2) {
            f16x8 pa = *(const f16x8*)&Ps[wave][lr][kk2 * 32 + lg * 8];
#pragma unroll
            for (int n = 0; n < 16; ++n) {
                f16x8 bv = *(const f16x8*)&B1[(n * 16 + lr) * 64 +
                                              ((kk2 * 32 + lg * 8) ^ vswz)];
                o[n] = __builtin_amdgcn_mfma_f32_16x16x32_f16(pa, bv, o[n], 0, 0, 0);
            }
        }
        __builtin_amdgcn_s_setprio(0);
        asm volatile("" ::: "memory");
        __builtin_amdgcn_s_barrier();          // B1 reads done before next V stage
        __builtin_amdgcn_sched_barrier(0);
    }

    // zero-fill strictly-masked P region for these 64 q rows
    int kstart = (qb + 1) * 64;
    if (kstart < SEQ) {
        f32x4 z = (f32x4){0.f, 0.f, 0.f, 0.f};
        for (int r = 0; r < 64; ++r) {
            float* rp = Pb + (size_t)(q0 + r) * SEQ;
            for (int c = kstart + tid * 4; c < SEQ; c += 1024)
                *(f32x4*)(rp + c) = z;
        }
    }

    // write O (f16) to [b, s, h*HD + d]
#pragma unroll
    for (int n = 0; n < 16; ++n) {
#pragma unroll
        for (int i = 0; i < 4; ++i) {
            int row = rowb + i;
            int d = n * 16 + lr;
            Oh[((size_t)b * SEQ + row) * DM + h * HD + d] = (f16)o[n][i];
        }
    }
}

// ---------------------------------------------------------------------------
extern "C" void kernel_launch(void* const* d_in, const int* in_sizes, int n_in,
                              void* d_out, int out_size, void* d_ws, size_t ws_size,
                              hipStream_t stream) {
    const float* x  = (const float*)d_in[0];
    const float* Wq = (const float*)d_in[1];
    const float* bq = (const float*)d_in[2];
    const float* Wk = (const float*)d_in[3];
    const float* bk = (const float*)d_in[4];
    const float* Wv = (const float*)d_in[5];
    const float* bv = (const float*)d_in[6];
    const float* Wo = (const float*)d_in[7];
    const float* bo = (const float*)d_in[8];

    float* out  = (float*)d_out;
    float* Pout = out + (size_t)MT * DM;          // attn_probs region (256MB)

    // f16 scratch for x and Wq/Wk/Wv parked inside the (not yet written) P
    // region of d_out; they are dead before k_attn overwrites that region.
    f16* xh  = (f16*)Pout;                         // 8388608 f16
    f16* Wqh = xh + (size_t)MT * DM;               // 4194304 f16 each
    f16* Wkh = Wqh + (size_t)DM * DM;
    f16* Wvh = Wkh + (size_t)DM * DM;

    // persistent f16 scratch in ws (must survive into/through k_attn)
    f16* ws16 = (f16*)d_ws;
    f16* Woh = ws16;                               // 4194304
    f16* Qh  = Woh + (size_t)DM * DM;              // 8388608
    f16* Kh  = Qh + (size_t)8388608;               // [b,h,s,d] = 8388608
    f16* Vth = Kh + (size_t)8388608;               // [b,h,d,s] = 8388608
    f16* Oh  = Vth + (size_t)8388608;              // [b,s,D]   = 8388608
    if (ws_size < (size_t)(4194304 + 4 * 8388608) * sizeof(f16)) return;

    // conversions
    k_cvt<<<2048, 256, 0, stream>>>(x, xh, MT * DM);
    k_cvt<<<1024, 256, 0, stream>>>(Wq, Wqh, DM * DM);
    k_cvt<<<1024, 256, 0, stream>>>(Wk, Wkh, DM * DM);
    k_cvt<<<1024, 256, 0, stream>>>(Wv, Wvh, DM * DM);
    k_cvt<<<1024, 256, 0, stream>>>(Wo, Woh, DM * DM);

    // QKV projections: 256x128 tiles -> 16 x 16 x 3 = 768 blocks (3/CU exact)
    dim3 g1(DM / 128, MT / 256, 3);
    k_proj_qkv<<<g1, 512, 0, stream>>>(xh, Wqh, Wkh, Wvh, bq, bk, bv, Qh, Kh, Vth);

    // fused causal attention + P materialization (XCD-locality 1D grid)
    k_attn<<<dim3(512), 256, 0, stream>>>(Qh, Kh, Vth, Pout, Oh);

    // output projection: 16 x 16 = 256 blocks (1/CU exact)
    dim3 g3(DM / 128, MT / 256, 1);
    k_proj_o<<<g3, 512, 0, stream>>>(Oh, Woh, bo, out);
}